// Round 1
// baseline (491.389 us; speedup 1.0000x reference)
//
#include <hip/hip_runtime.h>
#include <hip/hip_bf16.h>

#define N_SEND 12288
#define N_REC  49152
#define NEDGE  196608

typedef __attribute__((ext_vector_type(8))) short short8;
typedef __attribute__((ext_vector_type(4))) float floatx4;
typedef __attribute__((ext_vector_type(2))) float floatx2;

__device__ inline short f2bs(float f) {
    __hip_bfloat16 h = __float2bfloat16(f);
    return *reinterpret_cast<short*>(&h);
}
__device__ inline float bs2f(unsigned short u) {
    unsigned int x = ((unsigned int)u) << 16;
    return __builtin_bit_cast(float, x);
}
// jax.nn.gelu default approximate=True (tanh form)
__device__ inline float gelu_tanh(float x) {
    const float k0 = 0.7978845608028654f;
    float u = k0 * (x + 0.044715f * x * x * x);
    float e = __expf(2.0f * u);
    float t = 1.0f - 2.0f / (e + 1.0f);
    return 0.5f * x * (1.0f + t);
}

// ---------------- prep: MT = (We2 @ Wl1[256:])^T bf16, transposed bf16 weights, cvec ----
__global__ void prep_kernel(const float* __restrict__ We2, const float* __restrict__ be2,
                            const float* __restrict__ Wl1, const float* __restrict__ Wl2,
                            short* __restrict__ MT, short* __restrict__ WT1lo,
                            short* __restrict__ WT2, float* __restrict__ cvec) {
    int i = blockIdx.x;
    int n = threadIdx.x;
    if (i < 256) {
        float acc = 0.f;
        for (int j = 0; j < 256; ++j)
            acc += We2[i * 256 + j] * Wl1[(256 + j) * 256 + n];
        MT[n * 256 + i]    = f2bs(acc);                       // MT[n][k] = M[k][n]
        WT1lo[n * 256 + i] = f2bs(Wl1[i * 256 + n]);          // WT1lo[n][k] = Wl1[k][n], k<256
        WT2[n * 256 + i]   = f2bs(Wl2[i * 256 + n]);          // WT2[n][k] = Wl2[k][n]
    } else {
        float acc = 0.f;
        for (int j = 0; j < 256; ++j)
            acc += be2[j] * Wl1[(256 + j) * 256 + n];
        cvec[n] = acc;                                        // c = be2 @ Wl1[256:]
    }
}

// ---------------- shared GEMM pieces: 64-row x 256-col tile, K=256, BK=64 ----------------
// LDS A: 64 x 72 bf16 (pad 8), LDS B(T): 256 x 72 bf16.  4 waves, wave w = rows [16w,16w+16).
// A-frag: A[m=lane&15][k=quad*8+j]; B-frag: Bt[n=lane&15][k=quad*8+j]; C: col=lane&15,row=quad*4+reg.

__device__ inline void stage_B(const short* __restrict__ BT, short* Bl, int t, int kc) {
#pragma unroll
    for (int c = 0; c < 8; ++c) {
        short8 v = *(const short8*)(BT + t * 256 + kc + c * 8);
        *(short8*)(Bl + t * 72 + c * 8) = v;
    }
}

__device__ inline void mma_tile(const short* Al, const short* Bl,
                                floatx4 acc[16], int wrow, int m, int q) {
#pragma unroll
    for (int kk = 0; kk < 64; kk += 32) {
        short8 a = *(const short8*)(Al + (wrow + m) * 72 + kk + q * 8);
#pragma unroll
        for (int nt = 0; nt < 16; ++nt) {
            short8 b = *(const short8*)(Bl + (nt * 16 + m) * 72 + kk + q * 8);
            acc[nt] = __builtin_amdgcn_mfma_f32_16x16x32_bf16(a, b, acc[nt], 0, 0, 0);
        }
    }
}

// ---------------- K1: Y(24576x256 bf16) = bf16(X) @ WT1lo^T ----------------
__global__ __launch_bounds__(256, 3)
void gemm_y(const float* __restrict__ X, const short* __restrict__ WT1lo,
            short* __restrict__ Y) {
    __shared__ short Al[64 * 72];
    __shared__ short Bl[256 * 72];
    int t = threadIdx.x;
    int r0 = blockIdx.x * 64;
    int lane = t & 63, w = t >> 6, m = lane & 15, q = lane >> 4;
    floatx4 acc[16];
#pragma unroll
    for (int i = 0; i < 16; ++i) acc[i] = (floatx4){0.f, 0.f, 0.f, 0.f};
    int ar = t >> 2, acs = (t & 3) * 16;

    for (int kc = 0; kc < 256; kc += 64) {
        const float* src = X + (r0 + ar) * 256 + kc + acs;
        floatx4 v0 = *(const floatx4*)(src + 0);
        floatx4 v1 = *(const floatx4*)(src + 4);
        floatx4 v2 = *(const floatx4*)(src + 8);
        floatx4 v3 = *(const floatx4*)(src + 12);
        short8 p0, p1;
#pragma unroll
        for (int j = 0; j < 4; ++j) {
            p0[j] = f2bs(v0[j]); p0[j + 4] = f2bs(v1[j]);
            p1[j] = f2bs(v2[j]); p1[j + 4] = f2bs(v3[j]);
        }
        *(short8*)(Al + ar * 72 + acs) = p0;
        *(short8*)(Al + ar * 72 + acs + 8) = p1;
        stage_B(WT1lo, Bl, t, kc);
        __syncthreads();
        mma_tile(Al, Bl, acc, w * 16, m, q);
        __syncthreads();
    }
    int rbase = r0 + w * 16 + q * 4;
#pragma unroll
    for (int nt = 0; nt < 16; ++nt)
#pragma unroll
        for (int r = 0; r < 4; ++r)
            Y[(rbase + r) * 256 + nt * 16 + m] = f2bs(acc[nt][r]);
}

// ---------------- K2: G(E x 256 bf16) = gelu(ea@We1+be1) @ M + cvec ----------------
__global__ __launch_bounds__(256, 3)
void gemm_g(const float* __restrict__ EA, const float* __restrict__ We1,
            const float* __restrict__ be1, const short* __restrict__ MT,
            const float* __restrict__ cvec, short* __restrict__ G) {
    __shared__ short Al[64 * 72];
    __shared__ short Bl[256 * 72];
    int t = threadIdx.x;
    int e0 = blockIdx.x * 64;
    int lane = t & 63, w = t >> 6, m = lane & 15, q = lane >> 4;
    floatx4 acc[16];
#pragma unroll
    for (int i = 0; i < 16; ++i) acc[i] = (floatx4){0.f, 0.f, 0.f, 0.f};
    int ar = t >> 2, acs = (t & 3) * 16;
    floatx4 ea = *(const floatx4*)(EA + (e0 + ar) * 4);   // EIN=4 attrs for this row

    for (int kc = 0; kc < 256; kc += 64) {
        short8 p0, p1;
#pragma unroll
        for (int jj = 0; jj < 16; jj += 4) {
            int k = kc + acs + jj;
            floatx4 w0 = *(const floatx4*)(We1 + k);
            floatx4 w1 = *(const floatx4*)(We1 + 256 + k);
            floatx4 w2 = *(const floatx4*)(We1 + 512 + k);
            floatx4 w3 = *(const floatx4*)(We1 + 768 + k);
            floatx4 bb = *(const floatx4*)(be1 + k);
#pragma unroll
            for (int j2 = 0; j2 < 4; ++j2) {
                float h = ea[0] * w0[j2] + ea[1] * w1[j2] + ea[2] * w2[j2] + ea[3] * w3[j2] + bb[j2];
                float u = gelu_tanh(h);
                int j = jj + j2;
                if (j < 8) p0[j] = f2bs(u); else p1[j - 8] = f2bs(u);
            }
        }
        *(short8*)(Al + ar * 72 + acs) = p0;
        *(short8*)(Al + ar * 72 + acs + 8) = p1;
        stage_B(MT, Bl, t, kc);
        __syncthreads();
        mma_tile(Al, Bl, acc, w * 16, m, q);
        __syncthreads();
    }
    int rbase = e0 + w * 16 + q * 4;
#pragma unroll
    for (int nt = 0; nt < 16; ++nt) {
        float cv = cvec[nt * 16 + m];
#pragma unroll
        for (int r = 0; r < 4; ++r)
            G[(rbase + r) * 256 + nt * 16 + m] = f2bs(acc[nt][r] + cv);
    }
}

// ---------------- K3: S(2 x N_REC x 256 f32) = segsum(Y[send] + G) ----------------
// Block owns 16 receivers; edge range via binary search (idx_rec sorted). No atomics.
// Threads 0..127: b=0, threads 128..255: b=1; each thread covers cols {2c, 2c+1}.
__global__ __launch_bounds__(256)
void segsum(const int* __restrict__ idx_send, const int* __restrict__ idx_rec,
            const short* __restrict__ Y, const short* __restrict__ G,
            float* __restrict__ S) {
    int t = threadIdx.x;
    int r0 = blockIdx.x * 16;
    int b = t >> 7;
    int c = t & 127;

    int lo = 0, hi = NEDGE;
    while (lo < hi) { int mid = (lo + hi) >> 1; if (idx_rec[mid] < r0) lo = mid + 1; else hi = mid; }
    int e = lo;
    int lo2 = e, hi2 = NEDGE;
    while (lo2 < hi2) { int mid = (lo2 + hi2) >> 1; if (idx_rec[mid] < r0 + 16) lo2 = mid + 1; else hi2 = mid; }
    int eend = lo2;

    for (int r = r0; r < r0 + 16; ++r) {
        float a0 = 0.f, a1 = 0.f;
        while (e < eend && idx_rec[e] == r) {
            int sidx = idx_send[e];
            unsigned int gv = *(const unsigned int*)(G + e * 256 + 2 * c);
            unsigned int yv = *(const unsigned int*)(Y + (b * N_SEND + sidx) * 256 + 2 * c);
            a0 += bs2f((unsigned short)(gv & 0xffffu)) + bs2f((unsigned short)(yv & 0xffffu));
            a1 += bs2f((unsigned short)(gv >> 16)) + bs2f((unsigned short)(yv >> 16));
            ++e;
        }
        floatx2 o; o[0] = a0; o[1] = a1;
        *(floatx2*)(S + (b * N_REC + r) * 256 + 2 * c) = o;
    }
}

// ---------------- K4: OUT(2*N_REC x 256 f32) = bf16(gelu(S+bl1)) @ Wl2 + bl2 ----------------
__global__ __launch_bounds__(256, 3)
void gemm_out(const float* __restrict__ S, const float* __restrict__ bl1,
              const short* __restrict__ WT2, const float* __restrict__ bl2,
              float* __restrict__ OUT) {
    __shared__ short Al[64 * 72];
    __shared__ short Bl[256 * 72];
    int t = threadIdx.x;
    int r0 = blockIdx.x * 64;
    int lane = t & 63, w = t >> 6, m = lane & 15, q = lane >> 4;
    floatx4 acc[16];
#pragma unroll
    for (int i = 0; i < 16; ++i) acc[i] = (floatx4){0.f, 0.f, 0.f, 0.f};
    int ar = t >> 2, acs = (t & 3) * 16;

    for (int kc = 0; kc < 256; kc += 64) {
        const float* src = S + (r0 + ar) * 256 + kc + acs;
        const float* bp = bl1 + kc + acs;
        short8 p0, p1;
#pragma unroll
        for (int jj = 0; jj < 16; jj += 4) {
            floatx4 v = *(const floatx4*)(src + jj);
            floatx4 bb = *(const floatx4*)(bp + jj);
#pragma unroll
            for (int j2 = 0; j2 < 4; ++j2) {
                float u = gelu_tanh(v[j2] + bb[j2]);
                int j = jj + j2;
                if (j < 8) p0[j] = f2bs(u); else p1[j - 8] = f2bs(u);
            }
        }
        *(short8*)(Al + ar * 72 + acs) = p0;
        *(short8*)(Al + ar * 72 + acs + 8) = p1;
        stage_B(WT2, Bl, t, kc);
        __syncthreads();
        mma_tile(Al, Bl, acc, w * 16, m, q);
        __syncthreads();
    }
    int rbase = r0 + w * 16 + q * 4;
#pragma unroll
    for (int nt = 0; nt < 16; ++nt) {
        float bv = bl2[nt * 16 + m];
#pragma unroll
        for (int r = 0; r < 4; ++r)
            OUT[(rbase + r) * 256 + nt * 16 + m] = acc[nt][r] + bv;
    }
}

extern "C" void kernel_launch(void* const* d_in, const int* in_sizes, int n_in,
                              void* d_out, int out_size, void* d_ws, size_t ws_size,
                              hipStream_t stream) {
    const float* x        = (const float*)d_in[0];
    const float* ea       = (const float*)d_in[1];
    const int*   idx_send = (const int*)d_in[2];
    const int*   idx_rec  = (const int*)d_in[3];
    const float* We1      = (const float*)d_in[4];
    const float* be1      = (const float*)d_in[5];
    const float* We2      = (const float*)d_in[6];
    const float* be2      = (const float*)d_in[7];
    const float* Wl1      = (const float*)d_in[8];
    const float* bl1      = (const float*)d_in[9];
    const float* Wl2      = (const float*)d_in[10];
    const float* bl2      = (const float*)d_in[11];
    float* out = (float*)d_out;
    char*  ws  = (char*)d_ws;

    // workspace layout
    short* MT    = (short*)(ws);                         // 128 KB
    short* WT1lo = (short*)(ws + (1 << 17));             // 128 KB
    short* WT2   = (short*)(ws + (2 << 17));             // 128 KB
    float* cvec  = (float*)(ws + (3 << 17));             // 1 KB
    short* Y     = (short*)(ws + (4 << 17));             // 24576*256*2 = 12.6 MB
    short* G     = (short*)(ws + 524288 + 12582912);     // E*256*2 = 100.7 MB
    float* S     = (float*)(ws + 524288 + 12582912 + 100663296); // 100.7 MB

    prep_kernel<<<257, 256, 0, stream>>>(We2, be2, Wl1, Wl2, MT, WT1lo, WT2, cvec);
    gemm_y<<<(2 * N_SEND) / 64, 256, 0, stream>>>(x, WT1lo, Y);
    gemm_g<<<NEDGE / 64, 256, 0, stream>>>(ea, We1, be1, MT, cvec, G);
    segsum<<<N_REC / 16, 256, 0, stream>>>(idx_send, idx_rec, Y, G, S);
    gemm_out<<<(2 * N_REC) / 64, 256, 0, stream>>>(S, bl1, WT2, bl2, out);
}

// Round 2
// 324.741 us; speedup vs baseline: 1.5132x; 1.5132x over previous
//
#include <hip/hip_runtime.h>
#include <hip/hip_bf16.h>

#define N_SEND 12288
#define N_REC  49152
#define NEDGE  196608

typedef __attribute__((ext_vector_type(8))) short short8;
typedef __attribute__((ext_vector_type(4))) float floatx4;

__device__ inline short f2bs(float f) {
    __hip_bfloat16 h = __float2bfloat16(f);
    return *reinterpret_cast<short*>(&h);
}
__device__ inline float bs2f(unsigned int u16) {   // low 16 bits = bf16 pattern
    unsigned int x = u16 << 16;
    return __builtin_bit_cast(float, x);
}
__device__ inline unsigned int pack2(float a, float b) {
    unsigned int lo = (unsigned short)f2bs(a);
    unsigned int hi = (unsigned short)f2bs(b);
    return lo | (hi << 16);
}
// jax.nn.gelu default approximate=True (tanh form)
__device__ inline float gelu_tanh(float x) {
    const float k0 = 0.7978845608028654f;
    float u = k0 * (x + 0.044715f * x * x * x);
    float e = __expf(2.0f * u);
    float t = 1.0f - 2.0f / (e + 1.0f);
    return 0.5f * x * (1.0f + t);
}

// ---- prep: BT1[n][0:256]=Wl1lo^T, BT1[n][256:512]=(We2@Wl1hi)^T, WT2=Wl2^T, cvec=be2@Wl1hi
__global__ void prep_kernel(const float* __restrict__ We2, const float* __restrict__ be2,
                            const float* __restrict__ Wl1, const float* __restrict__ Wl2,
                            short* __restrict__ BT1, short* __restrict__ WT2,
                            float* __restrict__ cvec) {
    int i = blockIdx.x;
    int n = threadIdx.x;
    if (i < 256) {
        float acc = 0.f;
        for (int j = 0; j < 256; ++j)
            acc += We2[i * 256 + j] * Wl1[(256 + j) * 256 + n];
        BT1[n * 512 + i]       = f2bs(Wl1[i * 256 + n]);   // k<256: Wl1lo
        BT1[n * 512 + 256 + i] = f2bs(acc);                // k>=256: M = We2@Wl1hi
        WT2[n * 256 + i]       = f2bs(Wl2[i * 256 + n]);
    } else {
        float acc = 0.f;
        for (int j = 0; j < 256; ++j)
            acc += be2[j] * Wl1[(256 + j) * 256 + n];
        cvec[n] = acc;
    }
}

// ---- xcast: Xb = bf16(X), [2][N_SEND][256]
__global__ void xcast_kernel(const float* __restrict__ X, short* __restrict__ Xb) {
    int i = (blockIdx.x * 256 + threadIdx.x) * 8;
    floatx4 v0 = *(const floatx4*)(X + i);
    floatx4 v1 = *(const floatx4*)(X + i + 4);
    short8 p;
#pragma unroll
    for (int j = 0; j < 4; ++j) { p[j] = f2bs(v0[j]); p[j + 4] = f2bs(v1[j]); }
    *(short8*)(Xb + i) = p;
}

// ---- bounds: bnd[r] = lower_bound(idx_rec, r), r in [0, N_REC]
__global__ void bounds_kernel(const int* __restrict__ idx_rec, int* __restrict__ bnd) {
    int r = blockIdx.x * 256 + threadIdx.x;
    if (r > N_REC) return;
    int lo = 0, hi = NEDGE;
    while (lo < hi) { int mid = (lo + hi) >> 1; if (idx_rec[mid] < r) lo = mid + 1; else hi = mid; }
    bnd[r] = lo;
}

// ---- aggregate: Xagg[b][r][:] = sum_e X[b][send(e)][:];  Hagg[r][:] = sum_e gelu(ea@We1+be1)
// Block = 2 sub-blocks of 128 threads; sub-block owns 16 receivers; thread owns col pair {2c,2c+1}.
__global__ __launch_bounds__(256)
void aggregate(const int* __restrict__ idx_send, const int* __restrict__ bnd,
               const float* __restrict__ EA, const float* __restrict__ We1,
               const float* __restrict__ be1, const short* __restrict__ Xb,
               short* __restrict__ Xagg, short* __restrict__ Hagg) {
    __shared__ int sb[33];
    int t = threadIdx.x;
    int r0base = blockIdx.x * 32;
    if (t < 33) sb[t] = bnd[r0base + t];
    __syncthreads();
    int sub = t >> 7;
    int c = t & 127;
    int c2 = 2 * c;
    float w00 = We1[c2],       w01 = We1[c2 + 1];
    float w10 = We1[256 + c2], w11 = We1[256 + c2 + 1];
    float w20 = We1[512 + c2], w21 = We1[512 + c2 + 1];
    float w30 = We1[768 + c2], w31 = We1[768 + c2 + 1];
    float bb0 = be1[c2], bb1 = be1[c2 + 1];
    int rloc0 = sub * 16;

    for (int r = 0; r < 16; ++r) {
        int rr = r0base + rloc0 + r;
        int e0 = sb[rloc0 + r], e1 = sb[rloc0 + r + 1];
        float x00 = 0.f, x01 = 0.f, x10 = 0.f, x11 = 0.f, h0 = 0.f, h1 = 0.f;
#pragma unroll 2
        for (int e = e0; e < e1; ++e) {
            int s = idx_send[e];
            floatx4 a = *(const floatx4*)(EA + e * 4);
            unsigned int xv0 = *(const unsigned int*)(Xb + s * 256 + c2);
            unsigned int xv1 = *(const unsigned int*)(Xb + (N_SEND + s) * 256 + c2);
            x00 += bs2f(xv0 & 0xffffu); x01 += bs2f(xv0 >> 16);
            x10 += bs2f(xv1 & 0xffffu); x11 += bs2f(xv1 >> 16);
            float u0 = a[0] * w00 + a[1] * w10 + a[2] * w20 + a[3] * w30 + bb0;
            float u1 = a[0] * w01 + a[1] * w11 + a[2] * w21 + a[3] * w31 + bb1;
            h0 += gelu_tanh(u0); h1 += gelu_tanh(u1);
        }
        *(unsigned int*)(Xagg + (size_t)rr * 256 + c2)                     = pack2(x00, x01);
        *(unsigned int*)(Xagg + ((size_t)N_REC + rr) * 256 + c2)           = pack2(x10, x11);
        *(unsigned int*)(Hagg + (size_t)rr * 256 + c2)                     = pack2(h0, h1);
    }
}

// ---- shared MFMA tile helper (64x256 tile, BK=64) ----
__device__ inline void mma_tile(const short* Al, const short* Bl,
                                floatx4 acc[16], int wrow, int m, int q) {
#pragma unroll
    for (int kk = 0; kk < 64; kk += 32) {
        short8 a = *(const short8*)(Al + (wrow + m) * 72 + kk + q * 8);
#pragma unroll
        for (int nt = 0; nt < 16; ++nt) {
            short8 b = *(const short8*)(Bl + (nt * 16 + m) * 72 + kk + q * 8);
            acc[nt] = __builtin_amdgcn_mfma_f32_16x16x32_bf16(a, b, acc[nt], 0, 0, 0);
        }
    }
}

// ---- fused final: OUT = gelu([Xagg_b|Hagg]@BT1^T + cnt*cvec + bl1) @ WT2^T + bl2
__global__ __launch_bounds__(256, 2)
void gemm_fused(const short* __restrict__ Xagg, const short* __restrict__ Hagg,
                const short* __restrict__ BT1, const short* __restrict__ WT2,
                const float* __restrict__ cvec, const float* __restrict__ bl1,
                const float* __restrict__ bl2, const int* __restrict__ bnd,
                float* __restrict__ OUT) {
    __shared__ short Al[64 * 72];
    __shared__ short Bl[256 * 72];
    __shared__ short Tl[64 * 264];
    int t = threadIdx.x;
    int b = blockIdx.x / 768;
    int r0 = (blockIdx.x % 768) * 64;
    int lane = t & 63, w = t >> 6, m = lane & 15, q = lane >> 4;
    floatx4 acc[16];
#pragma unroll
    for (int i = 0; i < 16; ++i) acc[i] = (floatx4){0.f, 0.f, 0.f, 0.f};
    int ar = t >> 2, acs = (t & 3) * 16;
    const short* Arow0 = Xagg + ((size_t)b * N_REC + r0 + ar) * 256 + acs;
    const short* Arow1 = Hagg + ((size_t)(r0 + ar)) * 256 + acs;

    // ---- GEMM1: K=512 over [Xagg_b | Hagg] ----
    for (int kc = 0; kc < 512; kc += 64) {
        const short* src = (kc < 256) ? (Arow0 + kc) : (Arow1 + (kc - 256));
        *(short8*)(Al + ar * 72 + acs)     = *(const short8*)(src);
        *(short8*)(Al + ar * 72 + acs + 8) = *(const short8*)(src + 8);
#pragma unroll
        for (int cB = 0; cB < 8; ++cB)
            *(short8*)(Bl + t * 72 + cB * 8) = *(const short8*)(BT1 + t * 512 + kc + cB * 8);
        __syncthreads();
        mma_tile(Al, Bl, acc, w * 16, m, q);
        __syncthreads();
    }

    // ---- epilogue1: + cnt*cvec + bl1, gelu, bf16 -> Tl ----
    int rbl = w * 16 + q * 4;
    int rbase = r0 + rbl;
    int bv0 = bnd[rbase], bv1 = bnd[rbase + 1], bv2 = bnd[rbase + 2],
        bv3 = bnd[rbase + 3], bv4 = bnd[rbase + 4];
    float cnt[4] = {(float)(bv1 - bv0), (float)(bv2 - bv1),
                    (float)(bv3 - bv2), (float)(bv4 - bv3)};
#pragma unroll
    for (int nt = 0; nt < 16; ++nt) {
        int col = nt * 16 + m;
        float cv = cvec[col], b1v = bl1[col];
#pragma unroll
        for (int r = 0; r < 4; ++r) {
            float v = acc[nt][r] + cnt[r] * cv + b1v;
            Tl[(rbl + r) * 264 + col] = f2bs(gelu_tanh(v));
        }
        acc[nt] = (floatx4){0.f, 0.f, 0.f, 0.f};
    }

    // ---- GEMM2: K=256, A=Tl, B=WT2 ----
    for (int kc = 0; kc < 256; kc += 64) {
#pragma unroll
        for (int cB = 0; cB < 8; ++cB)
            *(short8*)(Bl + t * 72 + cB * 8) = *(const short8*)(WT2 + t * 256 + kc + cB * 8);
        __syncthreads();
#pragma unroll
        for (int kk = 0; kk < 64; kk += 32) {
            short8 a = *(const short8*)(Tl + (w * 16 + m) * 264 + kc + kk + q * 8);
#pragma unroll
            for (int nt = 0; nt < 16; ++nt) {
                short8 bf = *(const short8*)(Bl + (nt * 16 + m) * 72 + kk + q * 8);
                acc[nt] = __builtin_amdgcn_mfma_f32_16x16x32_bf16(a, bf, acc[nt], 0, 0, 0);
            }
        }
        __syncthreads();
    }

    // ---- epilogue2: + bl2, write f32 ----
#pragma unroll
    for (int nt = 0; nt < 16; ++nt) {
        int col = nt * 16 + m;
        float b2v = bl2[col];
#pragma unroll
        for (int r = 0; r < 4; ++r)
            OUT[((size_t)b * N_REC + rbase + r) * 256 + col] = acc[nt][r] + b2v;
    }
}

extern "C" void kernel_launch(void* const* d_in, const int* in_sizes, int n_in,
                              void* d_out, int out_size, void* d_ws, size_t ws_size,
                              hipStream_t stream) {
    const float* x        = (const float*)d_in[0];
    const float* ea       = (const float*)d_in[1];
    const int*   idx_send = (const int*)d_in[2];
    const int*   idx_rec  = (const int*)d_in[3];
    const float* We1      = (const float*)d_in[4];
    const float* be1      = (const float*)d_in[5];
    const float* We2      = (const float*)d_in[6];
    const float* be2      = (const float*)d_in[7];
    const float* Wl1      = (const float*)d_in[8];
    const float* bl1      = (const float*)d_in[9];
    const float* Wl2      = (const float*)d_in[10];
    const float* bl2      = (const float*)d_in[11];
    float* out = (float*)d_out;
    char*  ws  = (char*)d_ws;

    // workspace layout (bytes)
    short* BT1  = (short*)(ws + 0);           // 256*512*2   = 262144
    short* WT2  = (short*)(ws + 262144);      // 256*256*2   = 131072
    float* cvec = (float*)(ws + 393216);      // 1024
    int*   bnd  = (int*)  (ws + 397312);      // (N_REC+1)*4 = 196612
    short* Xb   = (short*)(ws + 1048576);     // 2*12288*256*2 = 12.6 MB
    short* Xagg = (short*)(ws + 16777216);    // 2*49152*256*2 = 50.3 MB
    short* Hagg = (short*)(ws + 67108864);    // 49152*256*2   = 25.2 MB

    prep_kernel<<<257, 256, 0, stream>>>(We2, be2, Wl1, Wl2, BT1, WT2, cvec);
    xcast_kernel<<<(2 * N_SEND * 256) / (256 * 8), 256, 0, stream>>>(x, Xb);
    bounds_kernel<<<(N_REC + 1 + 255) / 256, 256, 0, stream>>>(idx_rec, bnd);
    aggregate<<<N_REC / 32, 256, 0, stream>>>(idx_send, bnd, ea, We1, be1, Xb, Xagg, Hagg);
    gemm_fused<<<2 * 768, 256, 0, stream>>>(Xagg, Hagg, BT1, WT2, cvec, bl1, bl2, bnd, out);
}